// Round 1
// baseline (437.326 us; speedup 1.0000x reference)
//
#include <hip/hip_runtime.h>
#include <hip/hip_bf16.h>

#define NN 8192
#define FF 128

typedef unsigned short ushort_t;
typedef __attribute__((ext_vector_type(4))) float f32x4;
typedef __attribute__((ext_vector_type(8))) short s16x8;

__device__ __forceinline__ void block_sync_lds() {
  // CK-style barrier: wait LDS ops only, do NOT drain vmcnt -> global prefetch survives
  asm volatile("s_waitcnt lgkmcnt(0)\n\ts_barrier" ::: "memory");
}

// ---------------- Kernel 1: h = X @ W  -> hT (bf16, [128][8192]), s1, U=exp(s2), V=exp(.01 s2)
__global__ __launch_bounds__(256)
void k1_hw(const float* __restrict__ inp, const float* __restrict__ W,
           const float* __restrict__ a, ushort_t* __restrict__ hT,
           float* __restrict__ s1g, float* __restrict__ Ug, float* __restrict__ Vg)
{
  __shared__ float Wl[FF * FF];     // 64 KB
  __shared__ float il[32 * 129];    // padded, ~16 KB
  __shared__ float red1[32 * 8];
  __shared__ float red2[32 * 8];
  const int t = threadIdx.x;
  const int ib = blockIdx.x * 32;

  {
    const float4* Ws = (const float4*)W;
    float4* Wd = (float4*)Wl;
#pragma unroll
    for (int q = 0; q < 16; ++q) Wd[t + 256 * q] = Ws[t + 256 * q];
  }
#pragma unroll
  for (int q = 0; q < 4; ++q) {
    int idx = t + 256 * q;
    int r = idx >> 5, c4 = idx & 31;
    float4 v = ((const float4*)(inp + (size_t)(ib + r) * FF))[c4];
    float* dst = &il[r * 129 + c4 * 4];
    dst[0] = v.x; dst[1] = v.y; dst[2] = v.z; dst[3] = v.w;
  }
  __syncthreads();

  const int r = t & 31;
  const int c0 = (t >> 5) * 16;
  float acc[16];
#pragma unroll
  for (int j = 0; j < 16; ++j) acc[j] = 0.f;

#pragma unroll 4
  for (int k = 0; k < FF; ++k) {
    float iv = il[r * 129 + k];
    const float4* wrow = (const float4*)&Wl[k * FF + c0];
    float4 w0 = wrow[0], w1 = wrow[1], w2 = wrow[2], w3 = wrow[3];
    acc[0]  += iv * w0.x; acc[1]  += iv * w0.y; acc[2]  += iv * w0.z; acc[3]  += iv * w0.w;
    acc[4]  += iv * w1.x; acc[5]  += iv * w1.y; acc[6]  += iv * w1.z; acc[7]  += iv * w1.w;
    acc[8]  += iv * w2.x; acc[9]  += iv * w2.y; acc[10] += iv * w2.z; acc[11] += iv * w2.w;
    acc[12] += iv * w3.x; acc[13] += iv * w3.y; acc[14] += iv * w3.z; acc[15] += iv * w3.w;
  }

  float ps1 = 0.f, ps2 = 0.f;
#pragma unroll
  for (int q = 0; q < 4; ++q) {
    float4 a1v = *(const float4*)(a + c0 + 4 * q);
    float4 a2v = *(const float4*)(a + FF + c0 + 4 * q);
    ps1 += acc[4*q+0]*a1v.x + acc[4*q+1]*a1v.y + acc[4*q+2]*a1v.z + acc[4*q+3]*a1v.w;
    ps2 += acc[4*q+0]*a2v.x + acc[4*q+1]*a2v.y + acc[4*q+2]*a2v.z + acc[4*q+3]*a2v.w;
  }
  red1[r * 8 + (t >> 5)] = ps1;
  red2[r * 8 + (t >> 5)] = ps2;

#pragma unroll
  for (int j = 0; j < 16; ++j) {
    unsigned b = __float_as_uint(acc[j]);
    hT[(unsigned)(c0 + j) * NN + (unsigned)(ib + r)] = (ushort_t)((b + 0x8000u) >> 16);
  }
  __syncthreads();
  if (t < 32) {
    float s1 = 0.f, s2 = 0.f;
#pragma unroll
    for (int g2 = 0; g2 < 8; ++g2) { s1 += red1[t * 8 + g2]; s2 += red2[t * 8 + g2]; }
    s1g[ib + t] = s1;
    Ug[ib + t] = expf(s2);
    Vg[ib + t] = expf(0.01f * s2);
  }
}

// ---------------- Kernel 3: fused masked-softmax @ h via bf16 MFMA
// block: 32 output rows, 256 threads (4 waves: wr=wave>>1 row-half, wc=wave&1 col-half)
__global__ __launch_bounds__(256)
void k3_attn(const int* __restrict__ adj, const float* __restrict__ s1g,
             const float* __restrict__ Ug, const float* __restrict__ Vg,
             const ushort_t* __restrict__ hT, float* __restrict__ out)
{
  __shared__ ushort_t htl[2][64 * FF];  // [c][kslot] swizzled, 16 KB each
  __shared__ ushort_t wl[2][32 * 64];   // [i][j'] swizzled, 4 KB each
  __shared__ float zl[32];

  const int t = threadIdx.x;
  const int ib = blockIdx.x * 32;
  const int sj = t & 15, g = t >> 4;          // w-compute: rows g, g+16; cols sj*4..+3
  const int lane = t & 63, wv = t >> 6;
  const int wr = wv >> 1, wc = wv & 1;
  const int kidx = lane >> 4;
  const int arow = wr * 16 + (lane & 15);
  const int colbase = wc * 64 + (lane & 15);
  const int c_st = wv * 32 + (lane >> 3);     // hT staging: column (of h) this lane stages
  const int slot_st = lane & 7;               // which 8-element k-slot

  const float s1a = s1g[ib + g], s1b = s1g[ib + g + 16];
  const float la = s1a > 0.f ? s1a : 0.01f * s1a;
  const float lb = s1b > 0.f ? s1b : 0.01f * s1b;
  // m_i = leaky(s1)+24 (upper bound of row max; softmax shift-invariant)
  const float Pa = expf(s1a - la - 24.f), Qa = expf(0.01f * s1a - la - 24.f), Ea = expf(-s1a);
  const float Pb = expf(s1b - lb - 24.f), Qb = expf(0.01f * s1b - lb - 24.f), Eb = expf(-s1b);

  float z0 = 0.f, z1 = 0.f;
  f32x4 acc[4];
#pragma unroll
  for (int n = 0; n < 4; ++n) { acc[n][0] = 0.f; acc[n][1] = 0.f; acc[n][2] = 0.f; acc[n][3] = 0.f; }

  const int4* adjr0 = (const int4*)(adj + (size_t)(ib + g) * NN);
  const int4* adjr1 = (const int4*)(adj + (size_t)(ib + g + 16) * NN);
  const float4* Up = (const float4*)Ug;
  const float4* Vp = (const float4*)Vg;
  const ushort_t* hbase = hT + (size_t)c_st * NN + slot_st * 8;

  struct TileRegs { int4 A0, A1; float4 U4, V4; s16x8 H0, H1, H2, H3; };

  auto loadT = [&](TileRegs& R, int js) {
    const int i4 = js * 16 + sj;
    R.A0 = adjr0[i4];
    R.A1 = adjr1[i4];
    R.U4 = Up[i4];
    R.V4 = Vp[i4];
    const ushort_t* hs = hbase + js * 64;
    R.H0 = *(const s16x8*)(hs);
    R.H1 = *(const s16x8*)(hs + 8 * NN);
    R.H2 = *(const s16x8*)(hs + 16 * NN);
    R.H3 = *(const s16x8*)(hs + 24 * NN);
  };

  auto wquad = [&](const int4& A, const float4& Uv, const float4& Vv,
                   float P, float Q, float E, float& z) -> uint2 {
    float w0 = Uv.x > E ? P * Uv.x : Q * Vv.x;  w0 = A.x > 0 ? w0 : 0.f;
    float w1 = Uv.y > E ? P * Uv.y : Q * Vv.y;  w1 = A.y > 0 ? w1 : 0.f;
    float w2 = Uv.z > E ? P * Uv.z : Q * Vv.z;  w2 = A.z > 0 ? w2 : 0.f;
    float w3 = Uv.w > E ? P * Uv.w : Q * Vv.w;  w3 = A.w > 0 ? w3 : 0.f;
    z += (w0 + w1) + (w2 + w3);
    unsigned p0 = ((__float_as_uint(w0) + 0x8000u) >> 16) | ((__float_as_uint(w1) + 0x8000u) & 0xFFFF0000u);
    unsigned p1 = ((__float_as_uint(w2) + 0x8000u) >> 16) | ((__float_as_uint(w3) + 0x8000u) & 0xFFFF0000u);
    return make_uint2(p0, p1);
  };

  auto storeT = [&](int buf, const TileRegs& R) {
    // hT tile: linear src, XOR-swizzled LDS dest (16B granule ^ (row&7))
    char* hb = (char*)htl[buf] + c_st * 128 + ((slot_st ^ (c_st & 7)) << 4);
    *(s16x8*)(hb)            = R.H0;
    *(s16x8*)(hb + 8 * 128)  = R.H1;
    *(s16x8*)(hb + 16 * 128) = R.H2;
    *(s16x8*)(hb + 24 * 128) = R.H3;
    uint2 pa = wquad(R.A0, R.U4, R.V4, Pa, Qa, Ea, z0);
    uint2 pb = wquad(R.A1, R.U4, R.V4, Pb, Qb, Eb, z1);
    char* wb = (char*)wl[buf] + (((sj >> 1) ^ (g & 7)) << 4) + ((sj & 1) << 3);
    *(uint2*)(wb + g * 128)        = pa;
    *(uint2*)(wb + (g + 16) * 128) = pb;   // (g+16)&7 == g&7
  };

  auto domfma = [&](int buf) {
    const char* wb = (const char*)wl[buf];
    const char* hb = (const char*)htl[buf];
#pragma unroll
    for (int s = 0; s < 2; ++s) {
      const int kslot = s * 4 + kidx;
      s16x8 af = *(const s16x8*)(wb + arow * 128 + ((kslot ^ (arow & 7)) << 4));
#pragma unroll
      for (int n = 0; n < 4; ++n) {
        const int col = colbase + n * 16;
        s16x8 bf = *(const s16x8*)(hb + col * 128 + ((kslot ^ (col & 7)) << 4));
        acc[n] = __builtin_amdgcn_mfma_f32_16x16x32_bf16(af, bf, acc[n], 0, 0, 0);
      }
    }
  };

  TileRegs RA, RB;
  loadT(RA, 0);
  storeT(0, RA);        // tile 0 -> buf0
  loadT(RA, 1);
  loadT(RB, 2);
  block_sync_lds();

  for (int js = 0; js < 128; js += 2) {
    storeT(1, RA);                       // tile js+1 -> buf1 (always valid)
    if (js + 3 < 128) loadT(RA, js + 3); // prefetch
    domfma(0);                           // tile js
    block_sync_lds();
    if (js + 2 < 128) storeT(0, RB);     // tile js+2 -> buf0
    if (js + 4 < 128) loadT(RB, js + 4);
    domfma(1);                           // tile js+1
    block_sync_lds();
  }

  // Z reduction across the 16 lanes sharing a row-group
#pragma unroll
  for (int m = 1; m < 16; m <<= 1) {
    z0 += __shfl_xor(z0, m);
    z1 += __shfl_xor(z1, m);
  }
  if (sj == 0) { zl[g] = 1.f / z0; zl[g + 16] = 1.f / z1; }
  __syncthreads();

#pragma unroll
  for (int n = 0; n < 4; ++n) {
    const int col = colbase + n * 16;
#pragma unroll
    for (int r2 = 0; r2 < 4; ++r2) {
      const int row = wr * 16 + kidx * 4 + r2;   // C/D: col=lane&15, row=(lane>>4)*4+reg
      out[(size_t)(ib + row) * FF + col] = acc[n][r2] * zl[row];
    }
  }
}

extern "C" void kernel_launch(void* const* d_in, const int* in_sizes, int n_in,
                              void* d_out, int out_size, void* d_ws, size_t ws_size,
                              hipStream_t stream)
{
  const float* inp = (const float*)d_in[0];
  const int* adj   = (const int*)d_in[1];
  const float* W   = (const float*)d_in[2];
  const float* a   = (const float*)d_in[3];
  float* out = (float*)d_out;

  char* ws = (char*)d_ws;
  ushort_t* hT = (ushort_t*)ws;                                   // 2 MB
  float* s1g = (float*)(ws + (size_t)(2u << 20));                 // 32 KB
  float* Ug  = (float*)(ws + (size_t)(2u << 20) + (32u << 10));   // 32 KB
  float* Vg  = (float*)(ws + (size_t)(2u << 20) + (64u << 10));   // 32 KB

  hipLaunchKernelGGL(k1_hw, dim3(256), dim3(256), 0, stream, inp, W, a, hT, s1g, Ug, Vg);
  hipLaunchKernelGGL(k3_attn, dim3(256), dim3(256), 0, stream, adj, s1g, Ug, Vg, hT, out);
}